// Round 1
// 61.291 us; speedup vs baseline: 1.0128x; 1.0128x over previous
//
#include <hip/hip_runtime.h>
#include <hip/hip_bf16.h>
#include <float.h>
#include <math.h>

#define BB 64
#define T1 33
#define TT 32
#define II 197
#define CC 512
#define TEMP 0.07f

typedef __bf16 bf16x8 __attribute__((ext_vector_type(8)));
typedef float f32x4 __attribute__((ext_vector_type(4)));
typedef unsigned short u16x8 __attribute__((ext_vector_type(8)));

__device__ __forceinline__ unsigned short f32_to_bf16(float f) {
  unsigned int u = __float_as_uint(f);
  unsigned int r = u + 0x7FFFu + ((u >> 16) & 1u);  // RNE
  return (unsigned short)(r >> 16);
}

// ---- workspace layout (bytes) ----
// tl2: [8 xc8][16 kk][16 fa][64 lane][8] bf16  A-frags for 16x16x32:
//      row = fa*16 + (lane&15) = x_local*32 + t ; k = kk*32 + (lane>>4)*8 + j
// ve2: [64 y][16 kk][16 fb][64 lane][8] bf16  B-frags: col i = fb*16 + (lane&15)
// tti: [64 x][64 y] f32
#define TL_OFF  0
#define VE_OFF  2097152
#define TTI_OFF (2097152 + 16777216)   // 18874368

// grid (64, 8): hz 0..3 = video c-chunks, hz 4..7 = text c-chunks.
__global__ __launch_bounds__(256) void norm_all_kernel(const float* __restrict__ text,
                                                       const float* __restrict__ video,
                                                       unsigned short* __restrict__ tl2,
                                                       unsigned short* __restrict__ ve2) {
  int b = blockIdx.x, hz = blockIdx.y, tid = threadIdx.x;
  bool isV = hz < 4;
  int h2 = isV ? hz : hz - 4;
  const float* src = isV ? (video + (size_t)b * II * CC) : (text + (size_t)b * T1 * CC);
  int n = isV ? II : T1;

  __shared__ float red[8][128];
  __shared__ float rn[128];
  __shared__ unsigned short tile[2][16][136];

  // pass 1: sum of squares over axis=1, coalesced row reads
  {
    int c4 = tid & 31, rg = tid >> 5;
    const float* p = src + h2 * 128 + c4 * 4;
    float4 s = {0.f, 0.f, 0.f, 0.f};
    for (int i = rg; i < n; i += 8) {
      float4 v = *(const float4*)(p + (size_t)i * CC);
      s.x += v.x * v.x; s.y += v.y * v.y; s.z += v.z * v.z; s.w += v.w * v.w;
    }
    *(float4*)&red[rg][c4 * 4] = s;
  }
  __syncthreads();
  if (tid < 128) {
    float s = 0.f;
#pragma unroll
    for (int g = 0; g < 8; ++g) s += red[g][tid];
    rn[tid] = 1.0f / sqrtf(s);
  }
  __syncthreads();

  // pass 2: normalize + bf16 + frag-layout transpose via ping-pong LDS
  int nfb = isV ? 16 : 2;
  int row_l = tid >> 4, c8 = tid & 15;
  int q = tid >> 6, lane = tid & 63;
  int lim = isV ? II : 32;
  for (int fb = 0; fb < nfb; ++fb) {
    int pp = fb & 1;
    int i = fb * 16 + row_l;
    int isrc = isV ? i : (1 + i);
    float4 v0 = {0.f, 0.f, 0.f, 0.f}, v1 = {0.f, 0.f, 0.f, 0.f};
    if (i < lim) {
      const float* p = src + (size_t)isrc * CC + h2 * 128 + c8 * 8;
      v0 = *(const float4*)p;
      v1 = *(const float4*)(p + 4);
    }
    float4 r0 = *(const float4*)&rn[c8 * 8];
    float4 r1 = *(const float4*)&rn[c8 * 8 + 4];
    u16x8 o;
    o[0] = f32_to_bf16(v0.x * r0.x); o[1] = f32_to_bf16(v0.y * r0.y);
    o[2] = f32_to_bf16(v0.z * r0.z); o[3] = f32_to_bf16(v0.w * r0.w);
    o[4] = f32_to_bf16(v1.x * r1.x); o[5] = f32_to_bf16(v1.y * r1.y);
    o[6] = f32_to_bf16(v1.z * r1.z); o[7] = f32_to_bf16(v1.w * r1.w);
    *(u16x8*)&tile[pp][row_l][c8 * 8] = o;
    __syncthreads();

    int kgl = q * 4 + (lane >> 4), il = lane & 15;
    u16x8 t8 = *(const u16x8*)&tile[pp][il][kgl * 8];
    if (isV) {
      *(u16x8*)(ve2 + ((((size_t)b * 16 + h2 * 4 + q) * 16 + fb) * 64 + lane) * 8) = t8;
    } else {
      int xc = b >> 3, fa = (b & 7) * 2 + fb;
      *(u16x8*)(tl2 + ((((size_t)xc * 16 + h2 * 4 + q) * 16 + fa) * 64 + lane) * 8) = t8;
    }
  }
}

#define BITC(u) __builtin_bit_cast(bf16x8, u)

typedef __attribute__((address_space(3))) unsigned int lds_u32;
typedef __attribute__((address_space(1))) const unsigned int glb_u32;
__device__ __forceinline__ void gl16(const unsigned short* g, unsigned short* l) {
  __builtin_amdgcn_global_load_lds((glb_u32*)(const void*)g, (lds_u32*)(void*)l, 16, 0, 0);
}

// 1024 blocks x 512 threads, 2 blocks/CU (74 KB LDS, ~115 VGPR). Block (xcb, y):
// 128 rows (4 x's) x 256 cols, K=512 as 16 kk-phases. Wave tile 64x64.
// RING-3 slots + counted vmcnt(3): slot k+2 staged at phase-k top, so every
// stage has ~2 phases of latency cover and no phase drains vmcnt to 0
// (T3/T4). wn==3 waves trimmed to frag 12 only (cols >=208 are all past
// II=197): -18.75% CU-level MFMA work. setprio(1) around MFMA cluster (T5).
__global__ __launch_bounds__(512, 4) void sim_kernel(const unsigned short* __restrict__ tl2,
                                                     const unsigned short* __restrict__ ve2,
                                                     const int* __restrict__ mask,
                                                     float* __restrict__ tti) {
  int L = blockIdx.x;
  int xcd = L & 7;
  int idx = L >> 3;              // 0..127
  int y = xcd * 8 + (idx & 7);   // each XCD owns 8 consecutive y's
  int xcb = idx >> 3;            // 0..15 : 4 batch-x per block

  int tid = threadIdx.x;
  int w = tid >> 6, lane = tid & 63;
  int wm = w >> 2;               // 0..1 : rows wm*64..+64 (4 frags)
  int wn = w & 3;                // 0..3 : cols wn*64..+64 (4 frags)

  __shared__ unsigned short As[3 * 8 * 512];   // [slot][fa][lane*8] 24KB
  __shared__ unsigned short Bs[3 * 16 * 512];  // [slot][fb][lane*8] 48KB
  __shared__ float smax[4 * 128];              // [wn][row] 2KB

  // A chunk for this block: 8 contiguous fa frags within the xc8 group
  const unsigned short* Abase =
      tl2 + ((size_t)(xcb >> 1) * 16 * 16 + (xcb & 1) * 8) * 512;  // +kk*16*512
  const unsigned short* Bbase = ve2 + (size_t)y * 16 * 8192;

#define STG_A(k_) do {                                                        \
    const unsigned short* s_ = Abase + (size_t)(k_) * 8192 + w * 512 + lane * 8; \
    unsigned short* d_ = (unsigned short*)As + ((((k_) % 3)) * 8 + w) * 512;  \
    gl16(s_, d_);                                                             \
  } while (0)
#define STG_B(k_) do {                                                        \
    const unsigned short* s_ = Bbase + (size_t)(k_) * 8192 + (w * 2) * 512 + lane * 8; \
    unsigned short* d_ = (unsigned short*)Bs + ((((k_) % 3)) * 16 + w * 2) * 512; \
    gl16(s_, d_); gl16(s_ + 512, d_ + 512);                                   \
  } while (0)

  f32x4 acc[4][4] = {};

  // prologue: slots 0 and 1 staged; wait for slot 0 (3 newest ops may fly)
  STG_A(0); STG_B(0);
  STG_A(1); STG_B(1);
  asm volatile("s_waitcnt vmcnt(3)" ::: "memory");
  __builtin_amdgcn_s_barrier();

#pragma unroll
  for (int k = 0; k < 16; ++k) {
    if (k < 14) { STG_A(k + 2); STG_B(k + 2); }  // keep 2 slots in flight

    int slot = k % 3;  // compile-time (full unroll)
    u16x8 a[4], b[4];
#pragma unroll
    for (int ma = 0; ma < 4; ++ma)
      a[ma] = *(const u16x8*)&As[(slot * 8 + wm * 4 + ma) * 512 + lane * 8];

    if (wn == 3) {
      // cols 192..255: only frag 12 (cols 192..207) can contain i<197
      b[0] = *(const u16x8*)&Bs[(slot * 16 + 12) * 512 + lane * 8];
      __builtin_amdgcn_s_setprio(1);
#pragma unroll
      for (int ma = 0; ma < 4; ++ma)
        acc[ma][0] = __builtin_amdgcn_mfma_f32_16x16x32_bf16(
            BITC(a[ma]), BITC(b[0]), acc[ma][0], 0, 0, 0);
      __builtin_amdgcn_s_setprio(0);
    } else {
#pragma unroll
      for (int nb = 0; nb < 4; ++nb)
        b[nb] = *(const u16x8*)&Bs[(slot * 16 + wn * 4 + nb) * 512 + lane * 8];
      __builtin_amdgcn_s_setprio(1);
#pragma unroll
      for (int ma = 0; ma < 4; ++ma)
#pragma unroll
        for (int nb = 0; nb < 4; ++nb)
          acc[ma][nb] = __builtin_amdgcn_mfma_f32_16x16x32_bf16(
              BITC(a[ma]), BITC(b[nb]), acc[ma][nb], 0, 0, 0);
      __builtin_amdgcn_s_setprio(0);
    }

    if (k < 15) {
      // need slot k+1 landed; slot k+2's 3 ops/wave may stay in flight
      if (k < 14) asm volatile("s_waitcnt vmcnt(3)" ::: "memory");
      else        asm volatile("s_waitcnt vmcnt(0)" ::: "memory");
      __builtin_amdgcn_s_barrier();
    }
  }
#undef STG_A
#undef STG_B

  // ---- fused epilogue: max over i (i<197), masked mean over t -> tti ----
  int col = lane & 15, gq = lane >> 4;
  bool valid[4];
#pragma unroll
  for (int nb = 0; nb < 4; ++nb) valid[nb] = (wn * 64 + nb * 16 + col) < II;

  float mx[4][4];
#pragma unroll
  for (int ma = 0; ma < 4; ++ma)
#pragma unroll
    for (int reg = 0; reg < 4; ++reg) {
      float m = -FLT_MAX;
#pragma unroll
      for (int nb = 0; nb < 4; ++nb)
        if (valid[nb]) m = fmaxf(m, acc[ma][nb][reg]);
      mx[ma][reg] = m;
    }
#pragma unroll
  for (int st = 1; st <= 8; st <<= 1)
#pragma unroll
    for (int ma = 0; ma < 4; ++ma)
#pragma unroll
      for (int reg = 0; reg < 4; ++reg)
        mx[ma][reg] = fmaxf(mx[ma][reg], __shfl_xor(mx[ma][reg], st));

  if (col == 0) {
#pragma unroll
    for (int ma = 0; ma < 4; ++ma)
#pragma unroll
      for (int reg = 0; reg < 4; ++reg)
        smax[wn * 128 + wm * 64 + ma * 16 + gq * 4 + reg] = mx[ma][reg];
  }
  __syncthreads();

  if (tid < 128) {
    int r = tid;                       // row = x_local*32 + t
    float m = fmaxf(fmaxf(smax[r], smax[128 + r]),
                    fmaxf(smax[256 + r], smax[384 + r]));
    int x = xcb * 4 + (r >> 5), tt = r & 31;
    int mk = mask[x * T1 + 1 + tt];
    float num = mk ? m * TEMP : 0.f;
    float cnt = mk ? 1.f : 0.f;
#pragma unroll
    for (int st = 1; st < 32; st <<= 1) {
      num += __shfl_xor(num, st);
      cnt += __shfl_xor(cnt, st);
    }
    if (tt == 0) tti[x * 64 + y] = num / fmaxf(cnt, 1e-6f);
  }
}

// 1 block x 1024 threads: 16 threads per row x, each sums 4 y's.
__global__ void loss_kernel(const float* __restrict__ tti, float* __restrict__ out) {
  __shared__ float lxs[64];
  int tid = threadIdx.x;
  int x = tid >> 4, q = tid & 15;
  float4 v = *(const float4*)&tti[x * 64 + q * 4];
  float den = expf(v.x) + expf(v.y) + expf(v.z) + expf(v.w);
#pragma unroll
  for (int st = 1; st < 16; st <<= 1) den += __shfl_xor(den, st);
  if (q == 0) {
    float pos = expf(tti[x * 64 + x]);
    lxs[x] = -logf(pos / den + 1e-20f);
  }
  __syncthreads();
  if (tid < 64) {
    float lx = lxs[tid];
#pragma unroll
    for (int s = 1; s < 64; s <<= 1) lx += __shfl_xor(lx, s);
    if (tid == 0) out[0] = lx * (1.0f / 64.0f);
  }
}

extern "C" void kernel_launch(void* const* d_in, const int* in_sizes, int n_in,
                              void* d_out, int out_size, void* d_ws, size_t ws_size,
                              hipStream_t stream) {
  const float* text = (const float*)d_in[0];   // [64][33][512] f32
  const float* video = (const float*)d_in[1];  // [64][197][512] f32
  const int* mask = (const int*)d_in[2];       // [64][33] i32
  float* out = (float*)d_out;

  char* ws = (char*)d_ws;
  unsigned short* tl2 = (unsigned short*)(ws + TL_OFF);
  unsigned short* ve2 = (unsigned short*)(ws + VE_OFF);
  float* tti = (float*)(ws + TTI_OFF);

  hipLaunchKernelGGL(norm_all_kernel, dim3(BB, 8), dim3(256), 0, stream, text, video, tl2, ve2);
  hipLaunchKernelGGL(sim_kernel, dim3(1024), dim3(512), 0, stream, tl2, ve2, mask, tti);
  hipLaunchKernelGGL(loss_kernel, dim3(1), dim3(1024), 0, stream, tti, out);
}